// Round 4
// baseline (91.259 us; speedup 1.0000x reference)
//
#include <hip/hip_runtime.h>
#include <hip/hip_bf16.h>

#define NB 16
#define NT 512
#define NR 128
#define NV 64
#define RG 4   // ref_t points per block

__global__ __launch_bounds__(256) void interp_kernel(
    const float* __restrict__ x,
    const float* __restrict__ m,
    const float* __restrict__ t,
    const float* __restrict__ kern,
    const float* __restrict__ ref_t,
    float* __restrict__ out)
{
    __shared__ float ts[NT];
    __shared__ float red[4][4 * RG][NV];   // [chunk][j*4 + which][v] = 16 KiB

    const int tid   = threadIdx.x;
    const int v     = tid & 63;
    const int chunk = tid >> 6;            // 0..3 : quarter of the T axis
    const int bid   = blockIdx.x;
    const int b     = bid >> 5;            // NR/RG = 32 r-groups per batch
    const int rg    = bid & 31;
    const int r0    = rg * RG;

    // stage t[b,:] (2 KiB) into LDS for broadcast reads
    for (int i = tid; i < NT; i += 256) ts[i] = t[b * NT + i];

    // pos_kernel = softplus(kernel[v]); fold -pk into the exp argument
    const float kv  = kern[v];
    const float pk  = log1pf(__expf(kv));
    const float npk = -pk;

    float rt[RG];
#pragma unroll
    for (int j = 0; j < RG; ++j) rt[j] = ref_t[r0 + j];

    float lam[RG], sig[RG], lamh[RG], gam[RG];
#pragma unroll
    for (int j = 0; j < RG; ++j) { lam[j] = 0.f; sig[j] = 0.f; lamh[j] = 0.f; gam[j] = 0.f; }

    __syncthreads();

    const int t_base = chunk * (NT / 4);
    const float* __restrict__ xrow = x + (size_t)b * NT * NV + v;
    const float* __restrict__ mrow = m + (size_t)b * NT * NV + v;

    for (int i = 0; i < NT / 4; ++i) {
        const int tt   = t_base + i;
        const float tv = ts[tt];
        const float mv = mrow[(size_t)tt * NV];
        const float xv = xrow[(size_t)tt * NV];
        const float mx = mv * xv;
#pragma unroll
        for (int j = 0; j < RG; ++j) {
            const float dt  = tv - rt[j];
            const float wn  = npk * (dt * dt);     // -w
            const float e   = __expf(wn);          // exp(-w): 1 v_exp_f32
            const float e2  = e * e;
            const float e4  = e2 * e2;
            const float e8  = e4 * e4;
            const float e10 = e8 * e2;             // exp(-10w) via 4 muls
            lam[j]  = fmaf(e,   mv, lam[j]);
            sig[j]  = fmaf(e,   mx, sig[j]);
            lamh[j] = fmaf(e10, mv, lamh[j]);
            gam[j]  = fmaf(e10, mx, gam[j]);
        }
    }

    // write partials: [chunk][j*4+k][v] — 64 consecutive floats per row, conflict-free
#pragma unroll
    for (int j = 0; j < RG; ++j) {
        red[chunk][j * 4 + 0][v] = lam[j];
        red[chunk][j * 4 + 1][v] = sig[j];
        red[chunk][j * 4 + 2][v] = lamh[j];
        red[chunk][j * 4 + 3][v] = gam[j];
    }
    __syncthreads();

    // final reduce: thread (jj = chunk, v) owns output r = r0 + jj
    const int jj = chunk;
    float flam = 0.f, fsig = 0.f, flamh = 0.f, fgam = 0.f;
#pragma unroll
    for (int c = 0; c < 4; ++c) {
        flam  += red[c][jj * 4 + 0][v];
        fsig  += red[c][jj * 4 + 1][v];
        flamh += red[c][jj * 4 + 2][v];
        fgam  += red[c][jj * 4 + 3][v];
    }
    const float sigma = fsig / fmaxf(flam, 1.0f);
    const float gamma = fgam / fmaxf(flamh, 1.0f);

    const int r = r0 + jj;
    const size_t o = ((size_t)b * NR + r) * NV + v;
    out[o]                            = sigma;   // sigma  block (f32!)
    out[o + (size_t)NB * NR * NV]     = flam;    // lambda block
    out[o + (size_t)2 * NB * NR * NV] = gamma;   // gamma  block
}

extern "C" void kernel_launch(void* const* d_in, const int* in_sizes, int n_in,
                              void* d_out, int out_size, void* d_ws, size_t ws_size,
                              hipStream_t stream) {
    const float* x     = (const float*)d_in[0];
    const float* m     = (const float*)d_in[1];
    const float* t     = (const float*)d_in[2];
    // d_in[3] = h, unused by the reference
    const float* kern  = (const float*)d_in[4];
    const float* ref_t = (const float*)d_in[5];
    float* out = (float*)d_out;

    dim3 grid(NB * (NR / RG));   // 512 blocks
    dim3 block(256);
    interp_kernel<<<grid, block, 0, stream>>>(x, m, t, kern, ref_t, out);
}

// Round 5
// 89.702 us; speedup vs baseline: 1.0174x; 1.0174x over previous
//
#include <hip/hip_runtime.h>
#include <hip/hip_bf16.h>

#define NB 16
#define NT 512
#define NR 128
#define NV 64
#define RG 4    // ref_t points per block
#define NCH 8   // T-chunks per block (512 threads = 8 waves)

__global__ __launch_bounds__(512) void interp_kernel(
    const float* __restrict__ x,
    const float* __restrict__ m,
    const float* __restrict__ t,
    const float* __restrict__ kern,
    const float* __restrict__ ref_t,
    float* __restrict__ out)
{
    __shared__ float ts[NT];
    __shared__ float red[NCH][4 * RG][NV];   // 32 KiB

    const int tid   = threadIdx.x;
    const int v     = tid & 63;
    const int chunk = tid >> 6;            // 0..7 : eighth of the T axis
    const int bid   = blockIdx.x;
    const int b     = bid >> 5;            // NR/RG = 32 r-groups per batch
    const int rg    = bid & 31;
    const int r0    = rg * RG;

    // stage t[b,:] (2 KiB) into LDS for broadcast reads
    for (int i = tid; i < NT; i += 512) ts[i] = t[b * NT + i];

    // pos_kernel = softplus(kernel[v]); fold -pk into the exp argument
    const float kv  = kern[v];
    const float pk  = log1pf(__expf(kv));
    const float npk = -pk;

    float rt[RG];
#pragma unroll
    for (int j = 0; j < RG; ++j) rt[j] = ref_t[r0 + j];

    float lam[RG], sig[RG], lamh[RG], gam[RG];
#pragma unroll
    for (int j = 0; j < RG; ++j) { lam[j] = 0.f; sig[j] = 0.f; lamh[j] = 0.f; gam[j] = 0.f; }

    __syncthreads();

    const int t_base = chunk * (NT / NCH);
    const float* __restrict__ xrow = x + (size_t)b * NT * NV + v;
    const float* __restrict__ mrow = m + (size_t)b * NT * NV + v;

    for (int i = 0; i < NT / NCH; ++i) {
        const int tt   = t_base + i;
        const float tv = ts[tt];
        const float mv = mrow[(size_t)tt * NV];
        const float xv = xrow[(size_t)tt * NV];
        const float mx = mv * xv;
#pragma unroll
        for (int j = 0; j < RG; ++j) {
            const float dt  = tv - rt[j];
            const float wn  = npk * (dt * dt);     // -w
            const float e   = __expf(wn);          // exp(-w)   : trans pipe
            const float e10 = __expf(10.0f * wn);  // exp(-10w) : trans pipe (was 4 VALU muls)
            lam[j]  = fmaf(e,   mv, lam[j]);
            sig[j]  = fmaf(e,   mx, sig[j]);
            lamh[j] = fmaf(e10, mv, lamh[j]);
            gam[j]  = fmaf(e10, mx, gam[j]);
        }
    }

    // write partials: [chunk][j*4+k][v] — 64 consecutive floats per row, conflict-free
#pragma unroll
    for (int j = 0; j < RG; ++j) {
        red[chunk][j * 4 + 0][v] = lam[j];
        red[chunk][j * 4 + 1][v] = sig[j];
        red[chunk][j * 4 + 2][v] = lamh[j];
        red[chunk][j * 4 + 3][v] = gam[j];
    }
    __syncthreads();

    // final reduce: thread (jj = chunk 0..3, v) owns output r = r0 + jj
    if (chunk < RG) {
        const int jj = chunk;
        float flam = 0.f, fsig = 0.f, flamh = 0.f, fgam = 0.f;
#pragma unroll
        for (int c = 0; c < NCH; ++c) {
            flam  += red[c][jj * 4 + 0][v];
            fsig  += red[c][jj * 4 + 1][v];
            flamh += red[c][jj * 4 + 2][v];
            fgam  += red[c][jj * 4 + 3][v];
        }
        const float sigma = fsig / fmaxf(flam, 1.0f);
        const float gamma = fgam / fmaxf(flamh, 1.0f);

        const int r = r0 + jj;
        const size_t o = ((size_t)b * NR + r) * NV + v;
        out[o]                            = sigma;   // sigma  block
        out[o + (size_t)NB * NR * NV]     = flam;    // lambda block
        out[o + (size_t)2 * NB * NR * NV] = gamma;   // gamma  block
    }
}

extern "C" void kernel_launch(void* const* d_in, const int* in_sizes, int n_in,
                              void* d_out, int out_size, void* d_ws, size_t ws_size,
                              hipStream_t stream) {
    const float* x     = (const float*)d_in[0];
    const float* m     = (const float*)d_in[1];
    const float* t     = (const float*)d_in[2];
    // d_in[3] = h, unused by the reference
    const float* kern  = (const float*)d_in[4];
    const float* ref_t = (const float*)d_in[5];
    float* out = (float*)d_out;

    dim3 grid(NB * (NR / RG));   // 512 blocks
    dim3 block(512);             // 8 waves: 4 waves/SIMD at 2 blocks/CU
    interp_kernel<<<grid, block, 0, stream>>>(x, m, t, kern, ref_t, out);
}